// Round 9
// baseline (1340.026 us; speedup 1.0000x reference)
//
#include <hip/hip_runtime.h>
#include <hip/hip_bf16.h>
#include <cstdint>

#define B_ 8
#define S_ 2048
#define D_ 1024
#define F_ 4096
#define E_ 5

typedef __attribute__((ext_vector_type(4))) int      i32x4;
typedef __attribute__((ext_vector_type(4))) float    f32x4;
typedef __attribute__((ext_vector_type(4))) uint16_t u16x4;
typedef __attribute__((ext_vector_type(8))) uint16_t u16x8;

__device__ __forceinline__ float b2f(uint16_t u){
  union { uint32_t i; float f; } v; v.i = ((uint32_t)u) << 16; return v.f;
}
__device__ __forceinline__ uint16_t f2b(float f){
  union { float f; uint32_t i; } v; v.f = f;
  uint32_t x = v.i;
  uint32_t r = (x + 0x7FFFu + ((x >> 16) & 1u)) >> 16;
  return (uint16_t)r;
}
// direct global->LDS DMA, 16B per lane; lds ptr must be wave-uniform base
__device__ __forceinline__ void gload16B(const uint16_t* g, uint16_t* l){
  __builtin_amdgcn_global_load_lds(
      (const __attribute__((address_space(1))) void*)g,
      (__attribute__((address_space(3))) void*)l, 16, 0, 0);
}

// -------- x f32 -> bf16 ------------------------------------------------------
__global__ __launch_bounds__(256) void cvt_bf16(
    const float* __restrict__ src, uint16_t* __restrict__ dst, long n)
{
  long i = ((long)blockIdx.x * 256 + threadIdx.x) * 8;
  const long stride = (long)gridDim.x * 256 * 8;
  for (; i + 8 <= n; i += stride){
    f32x4 a = *(const f32x4*)(src + i);
    f32x4 b = *(const f32x4*)(src + i + 4);
    u16x8 r;
#pragma unroll
    for (int k = 0; k < 4; ++k){ r[k] = f2b(a[k]); r[4 + k] = f2b(b[k]); }
    *(u16x8*)(dst + i) = r;
  }
}

// -------- transpose+cvt: src f32 (R,C) -> dst bf16 (C,R), per blockIdx.z -----
__global__ __launch_bounds__(256) void transpose64(
    const float* __restrict__ src, uint16_t* __restrict__ dst, int R, int C)
{
  __shared__ uint16_t t[64][68];
  const size_t base = (size_t)blockIdx.z * R * C;
  const int r0 = blockIdx.x * 64, c0 = blockIdx.y * 64;
  const int tr = threadIdx.x >> 4;
  const int tc = (threadIdx.x & 15) * 4;
#pragma unroll
  for (int i = 0; i < 4; ++i){
    const int row = tr + i * 16;
    f32x4 v = *(const f32x4*)(src + base + (size_t)(r0 + row) * C + (c0 + tc));
    t[row][tc + 0] = f2b(v[0]); t[row][tc + 1] = f2b(v[1]);
    t[row][tc + 2] = f2b(v[2]); t[row][tc + 3] = f2b(v[3]);
  }
  __syncthreads();
#pragma unroll
  for (int i = 0; i < 4; ++i){
    const int orow = tr + i * 16;
    u16x4 v;
    v[0] = t[tc + 0][orow]; v[1] = t[tc + 1][orow];
    v[2] = t[tc + 2][orow]; v[3] = t[tc + 3][orow];
    *(u16x4*)(dst + base + (size_t)(c0 + orow) * R + (r0 + tc)) = v;
  }
}

// -------- transpose f32 (R,C) -> f32 (C,R) (for g1) --------------------------
__global__ __launch_bounds__(256) void transpose_f32(
    const float* __restrict__ src, float* __restrict__ dst, int R, int C)
{
  __shared__ float t[64][65];
  const int r0 = blockIdx.x * 64, c0 = blockIdx.y * 64;
  const int tr = threadIdx.x >> 4;
  const int tc = (threadIdx.x & 15) * 4;
#pragma unroll
  for (int i = 0; i < 4; ++i){
    const int row = tr + i * 16;
    f32x4 v = *(const f32x4*)(src + (size_t)(r0 + row) * C + (c0 + tc));
    t[row][tc + 0] = v[0]; t[row][tc + 1] = v[1];
    t[row][tc + 2] = v[2]; t[row][tc + 3] = v[3];
  }
  __syncthreads();
#pragma unroll
  for (int i = 0; i < 4; ++i){
    const int orow = tr + i * 16;
    f32x4 v;
    v[0] = t[tc + 0][orow]; v[1] = t[tc + 1][orow];
    v[2] = t[tc + 2][orow]; v[3] = t[tc + 3][orow];
    *(f32x4*)(dst + (size_t)(c0 + orow) * R + (r0 + tc)) = v;
  }
}

// -------- gate 1: h[b,path,f] = relu(x[b,0,:] @ W1)  (thread-per-f, bf16) ----
__global__ __launch_bounds__(256) void gate_h(
    const uint16_t* __restrict__ xb, const uint16_t* __restrict__ wiT,
    const uint16_t* __restrict__ swiT, const int* __restrict__ label,
    float* __restrict__ hbuf)
{
  const int f = blockIdx.x * 256 + threadIdx.x;
  const int path = blockIdx.y, b = blockIdx.z;
  const uint16_t* wrow = (path == 0)
      ? wiT  + ((size_t)label[b] * F_ + f) * D_
      : swiT + ((size_t)(path - 1) * F_ + f) * D_;
  __shared__ uint16_t xs[D_];
  const uint16_t* xr = xb + (size_t)b * S_ * D_;   // row 0
  *(u16x4*)(xs + threadIdx.x * 4) = *(const u16x4*)(xr + threadIdx.x * 4);
  __syncthreads();
  float acc = 0.f;
  for (int d = 0; d < D_; d += 8){
    u16x8 w = *(const u16x8*)(wrow + d);
    u16x8 xv = *(const u16x8*)(xs + d);
#pragma unroll
    for (int k = 0; k < 8; ++k) acc += b2f(xv[k]) * b2f(w[k]);
  }
  hbuf[(size_t)(b * 3 + path) * F_ + f] = fmaxf(acc, 0.f);
}

// -------- gate 2: gin[b,path,d] = h @ W2  (thread-per-d, bf16 rows) ----------
__global__ __launch_bounds__(256) void gate_row(
    const uint16_t* __restrict__ woT, const uint16_t* __restrict__ swoT,
    const int* __restrict__ label, const float* __restrict__ hbuf,
    float* __restrict__ gin)
{
  const int d = blockIdx.x * 256 + threadIdx.x;
  const int path = blockIdx.y, b = blockIdx.z;
  const uint16_t* wrow = (path == 0)
      ? woT  + ((size_t)label[b] * D_ + d) * F_
      : swoT + ((size_t)(path - 1) * D_ + d) * F_;
  __shared__ float hs[F_];
  const float* hb = hbuf + (size_t)(b * 3 + path) * F_;
  for (int i = threadIdx.x; i < F_; i += 256) hs[i] = hb[i];
  __syncthreads();
  float acc = 0.f;
  for (int f = 0; f < F_; f += 8){
    u16x8 w = *(const u16x8*)(wrow + f);
    f32x4 h0 = *(const f32x4*)(hs + f);
    f32x4 h1 = *(const f32x4*)(hs + f + 4);
    acc += h0[0]*b2f(w[0]) + h0[1]*b2f(w[1]) + h0[2]*b2f(w[2]) + h0[3]*b2f(w[3])
         + h1[0]*b2f(w[4]) + h1[1]*b2f(w[5]) + h1[2]*b2f(w[6]) + h1[3]*b2f(w[7]);
  }
  gin[(size_t)(b * 3 + path) * D_ + d] = acc;
}

// -------- gate 3a: ts[b,j] = relu(gin[b,:] @ g1[:,j])  via g1T rows ----------
__global__ __launch_bounds__(256) void gate_w1(
    const float* __restrict__ gin, const float* __restrict__ g1T,
    float* __restrict__ ts)
{
  const int j = blockIdx.x * 256 + threadIdx.x;
  const int b = blockIdx.y;
  __shared__ float gs[3 * D_];
  const float* g = gin + (size_t)b * 3 * D_;
  for (int i = threadIdx.x; i < 3 * D_; i += 256) gs[i] = g[i];
  __syncthreads();
  const float* grow = g1T + (size_t)j * (3 * D_);
  float acc = 0.f;
  for (int i = 0; i < 3 * D_; i += 4){
    f32x4 w = *(const f32x4*)(grow + i);
    f32x4 gv = *(const f32x4*)(gs + i);
    acc += gv[0]*w[0] + gv[1]*w[1] + gv[2]*w[2] + gv[3]*w[3];
  }
  ts[(size_t)b * D_ + j] = fmaxf(acc, 0.f);
}

// -------- gate 3b: wgate[b,:] = softmax(ts[b,:] @ g2) ------------------------
__global__ __launch_bounds__(256) void gate_w2(
    const float* __restrict__ ts, const float* __restrict__ g2,
    float* __restrict__ wgate)
{
  const int b = blockIdx.x;
  __shared__ float p0[256], p1[256], p2[256];
  const float* t = ts + (size_t)b * D_;
  float s0 = 0.f, s1 = 0.f, s2 = 0.f;
  const int j0 = threadIdx.x * 4;
#pragma unroll
  for (int jj = 0; jj < 4; ++jj){
    const float tv = t[j0 + jj];
    s0 += tv * g2[(j0 + jj) * 3 + 0];
    s1 += tv * g2[(j0 + jj) * 3 + 1];
    s2 += tv * g2[(j0 + jj) * 3 + 2];
  }
  p0[threadIdx.x] = s0; p1[threadIdx.x] = s1; p2[threadIdx.x] = s2;
  __syncthreads();
  for (int st = 128; st > 0; st >>= 1){
    if (threadIdx.x < st){
      p0[threadIdx.x] += p0[threadIdx.x + st];
      p1[threadIdx.x] += p1[threadIdx.x + st];
      p2[threadIdx.x] += p2[threadIdx.x + st];
    }
    __syncthreads();
  }
  if (threadIdx.x == 0){
    const float a = p0[0], c = p1[0], d = p2[0];
    const float m = fmaxf(a, fmaxf(c, d));
    const float e0 = expf(a - m), e1 = expf(c - m), e2 = expf(d - m);
    const float inv = 1.f / (e0 + e1 + e2);
    wgate[b * 3 + 0] = e0 * inv;
    wgate[b * 3 + 1] = e1 * inv;
    wgate[b * 3 + 2] = e2 * inv;
  }
}

// ---------------- main GEMM: C(128x128) per block, A(M,K) x BT(N,K)^T --------
// Guide's "minimum 2-phase" (T3) at BK=32 so dbuf LDS stays 32 KB (same
// residency as round-3 single-buffer): STAGE(next) issued BEFORE the MFMAs,
// one __syncthreads (vmcnt0+lgkm0+barrier) per K-tile AFTER them. 64B LDS
// rows also halve the fragment-read bank conflict (16-way -> 8-way).
// MODE 0: H = relu(A@B) bf16 | MODE 1: O = s*(A@B) f32 | MODE 2: O += s*(A@B)
template<int MODE>
__global__ __launch_bounds__(256) void gemm_bt(
    const uint16_t* __restrict__ Abase, size_t a_stride, int lda, int K,
    const uint16_t* __restrict__ Wexp, const uint16_t* __restrict__ Wsh,
    int path, int b0, const int* __restrict__ label,
    const float* __restrict__ wgate,
    void* __restrict__ Obase_, size_t o_stride, int ldo)
{
  __shared__ uint16_t As[2][128 * 32];   // [buf][m 128][k 32] linear, 8 KB each
  __shared__ uint16_t Bs[2][128 * 32];   // [buf][n 128][k 32] linear

  const int z  = blockIdx.z;
  const int b  = b0 + z;
  const int m0 = blockIdx.x * 128;
  const int n0 = blockIdx.y * 128;

  const uint16_t* A = Abase + (size_t)z * a_stride;
  const size_t wstride = (size_t)D_ * F_;
  const uint16_t* BT = (path == 0) ? Wexp + (size_t)label[b] * wstride
                                   : Wsh  + (size_t)(path - 1) * wstride;

  const int tid  = threadIdx.x;
  const int wave = tid >> 6;
  const int lane = tid & 63;

  // staging: wave w owns rows [w*32, w*32+32); per lane 16B at
  // row = w*32 + q*16 + (lane>>2), col = (lane&3)*8.  LDS linear offset of
  // that element = w*1024 + q*512 + lane*8  (base wave-uniform, +lane*16B HW).
  const uint16_t* gA = A  + (size_t)(m0 + wave * 32 + (lane >> 2)) * lda + (lane & 3) * 8;
  const uint16_t* gB = BT + (size_t)(n0 + wave * 32 + (lane >> 3 == lane >> 3 ? (lane >> 2) : 0)) * K + (lane & 3) * 8;

  f32x4 acc[4][4];
#pragma unroll
  for (int i = 0; i < 4; ++i)
#pragma unroll
    for (int j = 0; j < 4; ++j) acc[i][j] = (f32x4)0.0f;

  // fragment bases: row = lane&15 (+i*16, + wave-half*64), k = (lane>>4)*8
  const int fa = ((wave >> 1) * 64 + (lane & 15)) * 32 + (lane >> 4) * 8;
  const int fb = ((wave &  1) * 64 + (lane & 15)) * 32 + (lane >> 4) * 8;

#define STAGE32(sel, kt) do {                                              \
    const uint16_t* _ga = gA + (size_t)(kt) * 32;                          \
    const uint16_t* _gb = gB + (size_t)(kt) * 32;                          \
    _Pragma("unroll")                                                      \
    for (int q = 0; q < 2; ++q){                                           \
      gload16B(_ga + (size_t)q * 16 * lda, &As[sel][wave * 1024 + q * 512]); \
      gload16B(_gb + (size_t)q * 16 * K,   &Bs[sel][wave * 1024 + q * 512]); \
    }                                                                      \
  } while (0)

  const int KT = K >> 5;

  STAGE32(0, 0);
  __syncthreads();                        // tile 0 resident

  for (int kt = 0; kt < KT; ++kt){
    const int sel = kt & 1;
    if (kt + 1 < KT) STAGE32(sel ^ 1, kt + 1);   // next tile flies under MFMAs

    const uint16_t* pa = &As[sel][fa];
    const uint16_t* pb = &Bs[sel][fb];
    __builtin_amdgcn_s_setprio(1);
    i32x4 af[4], bf[4];
#pragma unroll
    for (int i = 0; i < 4; ++i) af[i] = *(const i32x4*)(pa + i * 512);
#pragma unroll
    for (int j = 0; j < 4; ++j) bf[j] = *(const i32x4*)(pb + j * 512);
#pragma unroll
    for (int i = 0; i < 4; ++i)
#pragma unroll
      for (int j = 0; j < 4; ++j)
        asm("v_mfma_f32_16x16x32_bf16 %0, %1, %2, %0"
            : "+v"(acc[i][j]) : "v"(af[i]), "v"(bf[j]));
    __builtin_amdgcn_s_setprio(0);

    if (kt + 1 < KT) __syncthreads();   // vmcnt(0)+lgkmcnt(0)+barrier:
                                        // next tile resident, sel reads done
  }
#undef STAGE32

  asm volatile("s_nop 7\n\ts_nop 7" ::);   // MFMA->VALU read hazard guard

  // C/D layout: col = lane&15, row = (lane>>4)*4 + reg   [m89-verified]
  const int orow0 = m0 + (wave >> 1) * 64 + (lane >> 4) * 4;
  const int ocol0 = n0 + (wave &  1) * 64 + (lane & 15);

  if constexpr (MODE == 0){
    uint16_t* O = (uint16_t*)Obase_ + (size_t)z * o_stride;
#pragma unroll
    for (int i = 0; i < 4; ++i)
#pragma unroll
      for (int j = 0; j < 4; ++j){
        const int col = ocol0 + j * 16;
#pragma unroll
        for (int r = 0; r < 4; ++r){
          const int row = orow0 + i * 16 + r;
          const float v = acc[i][j][r];
          O[(size_t)row * ldo + col] = f2b(v > 0.f ? v : 0.f);
        }
      }
  } else {
    float* O = (float*)Obase_ + (size_t)z * o_stride;
    const float scale = wgate[b * 3 + path];
#pragma unroll
    for (int i = 0; i < 4; ++i)
#pragma unroll
      for (int j = 0; j < 4; ++j){
        const int col = ocol0 + j * 16;
#pragma unroll
        for (int r = 0; r < 4; ++r){
          const int row = orow0 + i * 16 + r;
          const size_t idx = (size_t)row * ldo + col;
          float v = scale * acc[i][j][r];
          if constexpr (MODE == 2) v += O[idx];
          O[idx] = v;
        }
      }
  }
}

// ------------------------------- host ----------------------------------------
extern "C" void kernel_launch(void* const* d_in, const int* in_sizes, int n_in,
                              void* d_out, int out_size, void* d_ws, size_t ws_size,
                              hipStream_t stream)
{
  (void)in_sizes; (void)n_in; (void)out_size;
  const float* x    = (const float*)d_in[0];
  const int*   label= (const int*)d_in[1];
  const float* wi   = (const float*)d_in[2];
  const float* wo   = (const float*)d_in[3];
  const float* swi  = (const float*)d_in[4];
  const float* swo  = (const float*)d_in[5];
  const float* g1   = (const float*)d_in[6];
  const float* g2   = (const float*)d_in[7];
  float* out = (float*)d_out;

  char* ws = (char*)d_ws;
  float* wgate = (float*)ws;                                 // 256 B
  float* gin   = (float*)(ws + 256);                         // B*3*D f32
  float* hbuf  = (float*)(ws + 98560);                       // B*3*F f32
  float* ts    = (float*)(ws + 491776);                      // B*D f32
  float* g1T   = (float*)(ws + (1u << 20));                  // D x 3D f32
  uint16_t* xb = (uint16_t*)(ws + (16u << 20));              // B*S*D bf16
  size_t off = (size_t)(16u << 20) + (size_t)B_ * S_ * D_ * 2;
  uint16_t* wiT  = (uint16_t*)(ws + off); off += (size_t)E_ * D_ * F_ * 2;  // (E,F,D)
  uint16_t* swiT = (uint16_t*)(ws + off); off += (size_t)2  * D_ * F_ * 2;  // (2,F,D)
  uint16_t* woT  = (uint16_t*)(ws + off); off += (size_t)E_ * D_ * F_ * 2;  // (E,D,F)
  uint16_t* swoT = (uint16_t*)(ws + off); off += (size_t)2  * D_ * F_ * 2;  // (2,D,F)
  uint16_t* H    = (uint16_t*)(ws + off);
  const size_t hbytes = (size_t)S_ * F_ * 2;
  const size_t hcap = (ws_size > off) ? (ws_size - off) / hbytes : 0;
  const int nb = hcap >= 8 ? 8 : hcap >= 4 ? 4 : hcap >= 2 ? 2 : 1;

  // prep: x -> bf16; weights -> transposed bf16; g1 -> transposed f32
  cvt_bf16<<<dim3(2048), 256, 0, stream>>>(x, xb, (long)B_ * S_ * D_);
  transpose64<<<dim3(D_/64, F_/64, E_), 256, 0, stream>>>(wi,  wiT,  D_, F_);
  transpose64<<<dim3(D_/64, F_/64, 2 ), 256, 0, stream>>>(swi, swiT, D_, F_);
  transpose64<<<dim3(F_/64, D_/64, E_), 256, 0, stream>>>(wo,  woT,  F_, D_);
  transpose64<<<dim3(F_/64, D_/64, 2 ), 256, 0, stream>>>(swo, swoT, F_, D_);
  transpose_f32<<<dim3(3*D_/64, D_/64), 256, 0, stream>>>(g1, g1T, 3*D_, D_);

  // gate: row-0 outputs -> gin -> ts -> softmax weights
  gate_h  <<<dim3(F_/256, 3, B_), 256, 0, stream>>>(xb, wiT, swiT, label, hbuf);
  gate_row<<<dim3(D_/256, 3, B_), 256, 0, stream>>>(woT, swoT, label, hbuf, gin);
  gate_w1 <<<dim3(D_/256, B_),    256, 0, stream>>>(gin, g1T, ts);
  gate_w2 <<<dim3(B_),            256, 0, stream>>>(ts, g2, wgate);

  const size_t SD = (size_t)S_ * D_;
  const size_t SF = (size_t)S_ * F_;
  for (int path = 0; path < 3; ++path){
    for (int b0 = 0; b0 < B_; b0 += nb){
      const int nbc = (b0 + nb <= B_) ? nb : (B_ - b0);
      gemm_bt<0><<<dim3(S_/128, F_/128, nbc), 256, 0, stream>>>(
          xb + (size_t)b0 * SD, SD, D_, D_, wiT, swiT, path, b0, label,
          (const float*)nullptr, H, SF, F_);
      if (path == 0)
        gemm_bt<1><<<dim3(S_/128, D_/128, nbc), 256, 0, stream>>>(
            H, SF, F_, F_, woT, swoT, path, b0, label, wgate,
            out + (size_t)b0 * SD, SD, D_);
      else
        gemm_bt<2><<<dim3(S_/128, D_/128, nbc), 256, 0, stream>>>(
            H, SF, F_, F_, woT, swoT, path, b0, label, wgate,
            out + (size_t)b0 * SD, SD, D_);
    }
  }
}

// Round 10
// 1159.506 us; speedup vs baseline: 1.1557x; 1.1557x over previous
//
#include <hip/hip_runtime.h>
#include <hip/hip_bf16.h>
#include <cstdint>

#define B_ 8
#define S_ 2048
#define D_ 1024
#define F_ 4096
#define E_ 5

typedef __attribute__((ext_vector_type(4))) int      i32x4;
typedef __attribute__((ext_vector_type(4))) float    f32x4;
typedef __attribute__((ext_vector_type(4))) uint16_t u16x4;
typedef __attribute__((ext_vector_type(8))) uint16_t u16x8;

__device__ __forceinline__ float b2f(uint16_t u){
  union { uint32_t i; float f; } v; v.i = ((uint32_t)u) << 16; return v.f;
}
__device__ __forceinline__ uint16_t f2b(float f){
  union { float f; uint32_t i; } v; v.f = f;
  uint32_t x = v.i;
  uint32_t r = (x + 0x7FFFu + ((x >> 16) & 1u)) >> 16;
  return (uint16_t)r;
}
// direct global->LDS DMA, 16B per lane; lds ptr must be wave-uniform base
__device__ __forceinline__ void gload16B(const uint16_t* g, uint16_t* l){
  __builtin_amdgcn_global_load_lds(
      (const __attribute__((address_space(1))) void*)g,
      (__attribute__((address_space(3))) void*)l, 16, 0, 0);
}

// -------- x f32 -> bf16 ------------------------------------------------------
__global__ __launch_bounds__(256) void cvt_bf16(
    const float* __restrict__ src, uint16_t* __restrict__ dst, long n)
{
  long i = ((long)blockIdx.x * 256 + threadIdx.x) * 8;
  const long stride = (long)gridDim.x * 256 * 8;
  for (; i + 8 <= n; i += stride){
    f32x4 a = *(const f32x4*)(src + i);
    f32x4 b = *(const f32x4*)(src + i + 4);
    u16x8 r;
#pragma unroll
    for (int k = 0; k < 4; ++k){ r[k] = f2b(a[k]); r[4 + k] = f2b(b[k]); }
    *(u16x8*)(dst + i) = r;
  }
}

// -------- transpose+cvt: src f32 (R,C) -> dst bf16 (C,R), per blockIdx.z -----
__global__ __launch_bounds__(256) void transpose64(
    const float* __restrict__ src, uint16_t* __restrict__ dst, int R, int C)
{
  __shared__ uint16_t t[64][68];
  const size_t base = (size_t)blockIdx.z * R * C;
  const int r0 = blockIdx.x * 64, c0 = blockIdx.y * 64;
  const int tr = threadIdx.x >> 4;
  const int tc = (threadIdx.x & 15) * 4;
#pragma unroll
  for (int i = 0; i < 4; ++i){
    const int row = tr + i * 16;
    f32x4 v = *(const f32x4*)(src + base + (size_t)(r0 + row) * C + (c0 + tc));
    t[row][tc + 0] = f2b(v[0]); t[row][tc + 1] = f2b(v[1]);
    t[row][tc + 2] = f2b(v[2]); t[row][tc + 3] = f2b(v[3]);
  }
  __syncthreads();
#pragma unroll
  for (int i = 0; i < 4; ++i){
    const int orow = tr + i * 16;
    u16x4 v;
    v[0] = t[tc + 0][orow]; v[1] = t[tc + 1][orow];
    v[2] = t[tc + 2][orow]; v[3] = t[tc + 3][orow];
    *(u16x4*)(dst + base + (size_t)(c0 + orow) * R + (r0 + tc)) = v;
  }
}

// -------- transpose f32 (R,C) -> f32 (C,R) (for g1) --------------------------
__global__ __launch_bounds__(256) void transpose_f32(
    const float* __restrict__ src, float* __restrict__ dst, int R, int C)
{
  __shared__ float t[64][65];
  const int r0 = blockIdx.x * 64, c0 = blockIdx.y * 64;
  const int tr = threadIdx.x >> 4;
  const int tc = (threadIdx.x & 15) * 4;
#pragma unroll
  for (int i = 0; i < 4; ++i){
    const int row = tr + i * 16;
    f32x4 v = *(const f32x4*)(src + (size_t)(r0 + row) * C + (c0 + tc));
    t[row][tc + 0] = v[0]; t[row][tc + 1] = v[1];
    t[row][tc + 2] = v[2]; t[row][tc + 3] = v[3];
  }
  __syncthreads();
#pragma unroll
  for (int i = 0; i < 4; ++i){
    const int orow = tr + i * 16;
    f32x4 v;
    v[0] = t[tc + 0][orow]; v[1] = t[tc + 1][orow];
    v[2] = t[tc + 2][orow]; v[3] = t[tc + 3][orow];
    *(f32x4*)(dst + (size_t)(c0 + orow) * R + (r0 + tc)) = v;
  }
}

// ---- gate 1 (wave-per-f): h[b,path,f] = relu(dot(x[b,0,:], W1row_f)) --------
// lanes read contiguous 16B segments of the weight row (coalesced 1KB/wave)
__global__ __launch_bounds__(256) void gate_h(
    const uint16_t* __restrict__ xb, const uint16_t* __restrict__ wiT,
    const uint16_t* __restrict__ swiT, const int* __restrict__ label,
    float* __restrict__ hbuf)
{
  const int wv = threadIdx.x >> 6, lane = threadIdx.x & 63;
  const int f = blockIdx.x * 4 + wv;          // grid.x = F/4
  const int path = blockIdx.y, b = blockIdx.z;
  const uint16_t* wrow = (path == 0)
      ? wiT  + ((size_t)label[b] * F_ + f) * D_
      : swiT + ((size_t)(path - 1) * F_ + f) * D_;
  const uint16_t* xr = xb + (size_t)b * S_ * D_;   // row 0 of batch b
  float acc = 0.f;
#pragma unroll
  for (int c = 0; c < 2; ++c){                 // D=1024 = 2 x (64 lanes x 8)
    const int off = c * 512 + lane * 8;
    u16x8 w  = *(const u16x8*)(wrow + off);
    u16x8 xv = *(const u16x8*)(xr + off);
#pragma unroll
    for (int k = 0; k < 8; ++k) acc += b2f(xv[k]) * b2f(w[k]);
  }
#pragma unroll
  for (int o = 32; o > 0; o >>= 1) acc += __shfl_down(acc, o);
  if (lane == 0)
    hbuf[(size_t)(b * 3 + path) * F_ + f] = fmaxf(acc, 0.f);
}

// ---- gate 2 (wave-per-d): gin[b,path,d] = dot(h[b,path,:], W2row_d) ---------
__global__ __launch_bounds__(256) void gate_row(
    const uint16_t* __restrict__ woT, const uint16_t* __restrict__ swoT,
    const int* __restrict__ label, const float* __restrict__ hbuf,
    float* __restrict__ gin)
{
  const int wv = threadIdx.x >> 6, lane = threadIdx.x & 63;
  const int d = blockIdx.x * 4 + wv;          // grid.x = D/4
  const int path = blockIdx.y, b = blockIdx.z;
  const uint16_t* wrow = (path == 0)
      ? woT  + ((size_t)label[b] * D_ + d) * F_
      : swoT + ((size_t)(path - 1) * D_ + d) * F_;
  const float* hb = hbuf + (size_t)(b * 3 + path) * F_;
  float acc = 0.f;
#pragma unroll
  for (int c = 0; c < 8; ++c){                 // F=4096 = 8 x (64 lanes x 8)
    const int off = c * 512 + lane * 8;
    u16x8 w  = *(const u16x8*)(wrow + off);
    f32x4 h0 = *(const f32x4*)(hb + off);
    f32x4 h1 = *(const f32x4*)(hb + off + 4);
    acc += h0[0]*b2f(w[0]) + h0[1]*b2f(w[1]) + h0[2]*b2f(w[2]) + h0[3]*b2f(w[3])
         + h1[0]*b2f(w[4]) + h1[1]*b2f(w[5]) + h1[2]*b2f(w[6]) + h1[3]*b2f(w[7]);
  }
#pragma unroll
  for (int o = 32; o > 0; o >>= 1) acc += __shfl_down(acc, o);
  if (lane == 0)
    gin[(size_t)(b * 3 + path) * D_ + d] = acc;
}

// ---- gate 3a (wave-per-j): ts[b,j] = relu(dot(gin[b,:], g1Trow_j)) ----------
__global__ __launch_bounds__(256) void gate_w1(
    const float* __restrict__ gin, const float* __restrict__ g1T,
    float* __restrict__ ts)
{
  const int wv = threadIdx.x >> 6, lane = threadIdx.x & 63;
  const int j = blockIdx.x * 4 + wv;          // grid.x = D/4
  const int b = blockIdx.y;
  const float* grow = g1T + (size_t)j * (3 * D_);
  const float* g = gin + (size_t)b * 3 * D_;
  float acc = 0.f;
#pragma unroll
  for (int c = 0; c < 12; ++c){                // 3D=3072 = 12 x (64 lanes x 4)
    const int off = c * 256 + lane * 4;
    f32x4 w  = *(const f32x4*)(grow + off);
    f32x4 gv = *(const f32x4*)(g + off);
    acc += gv[0]*w[0] + gv[1]*w[1] + gv[2]*w[2] + gv[3]*w[3];
  }
#pragma unroll
  for (int o = 32; o > 0; o >>= 1) acc += __shfl_down(acc, o);
  if (lane == 0)
    ts[(size_t)b * D_ + j] = fmaxf(acc, 0.f);
}

// -------- gate 3b: wgate[b,:] = softmax(ts[b,:] @ g2) ------------------------
__global__ __launch_bounds__(256) void gate_w2(
    const float* __restrict__ ts, const float* __restrict__ g2,
    float* __restrict__ wgate)
{
  const int b = blockIdx.x;
  __shared__ float p0[256], p1[256], p2[256];
  const float* t = ts + (size_t)b * D_;
  float s0 = 0.f, s1 = 0.f, s2 = 0.f;
  const int j0 = threadIdx.x * 4;
#pragma unroll
  for (int jj = 0; jj < 4; ++jj){
    const float tv = t[j0 + jj];
    s0 += tv * g2[(j0 + jj) * 3 + 0];
    s1 += tv * g2[(j0 + jj) * 3 + 1];
    s2 += tv * g2[(j0 + jj) * 3 + 2];
  }
  p0[threadIdx.x] = s0; p1[threadIdx.x] = s1; p2[threadIdx.x] = s2;
  __syncthreads();
  for (int st = 128; st > 0; st >>= 1){
    if (threadIdx.x < st){
      p0[threadIdx.x] += p0[threadIdx.x + st];
      p1[threadIdx.x] += p1[threadIdx.x + st];
      p2[threadIdx.x] += p2[threadIdx.x + st];
    }
    __syncthreads();
  }
  if (threadIdx.x == 0){
    const float a = p0[0], c = p1[0], d = p2[0];
    const float m = fmaxf(a, fmaxf(c, d));
    const float e0 = expf(a - m), e1 = expf(c - m), e2 = expf(d - m);
    const float inv = 1.f / (e0 + e1 + e2);
    wgate[b * 3 + 0] = e0 * inv;
    wgate[b * 3 + 1] = e1 * inv;
    wgate[b * 3 + 2] = e2 * inv;
  }
}

// ---------------- main GEMM: C(128x128) per block, A(M,K) x BT(N,K)^T --------
// Round-3/8 verified structure EXACT (best measured: 1271 us, 190 us/dispatch).
// MODE 0: H = relu(A@B) bf16 | MODE 1: O = s*(A@B) f32 | MODE 2: O += s*(A@B)
template<int MODE>
__global__ __launch_bounds__(256) void gemm_bt(
    const uint16_t* __restrict__ Abase, size_t a_stride, int lda, int K,
    const uint16_t* __restrict__ Wexp, const uint16_t* __restrict__ Wsh,
    int path, int b0, const int* __restrict__ label,
    const float* __restrict__ wgate,
    void* __restrict__ Obase_, size_t o_stride, int ldo)
{
  __shared__ uint16_t As[128 * 64];   // [m 128][k 64] linear
  __shared__ uint16_t Bs[128 * 64];   // [n 128][k 64] linear

  const int z  = blockIdx.z;
  const int b  = b0 + z;
  const int m0 = blockIdx.x * 128;
  const int n0 = blockIdx.y * 128;

  const uint16_t* A = Abase + (size_t)z * a_stride;
  const size_t wstride = (size_t)D_ * F_;
  const uint16_t* BT = (path == 0) ? Wexp + (size_t)label[b] * wstride
                                   : Wsh  + (size_t)(path - 1) * wstride;

  const int tid  = threadIdx.x;
  const int wave = tid >> 6;
  const int lane = tid & 63;

  // global addresses: per-lane; LDS dest: wave-uniform base (+lane*16B by HW)
  const uint16_t* gA = A  + (size_t)(m0 + wave * 8 + (lane >> 3)) * lda + (lane & 7) * 8;
  const uint16_t* gB = BT + (size_t)(n0 + wave * 8 + (lane >> 3)) * K   + (lane & 7) * 8;
  uint16_t* lA = As + wave * 512;
  uint16_t* lB = Bs + wave * 512;

  f32x4 acc[4][4];
#pragma unroll
  for (int i = 0; i < 4; ++i)
#pragma unroll
    for (int j = 0; j < 4; ++j) acc[i][j] = (f32x4)0.0f;

  // fragment read bases: row = lane&15, k = (lane>>4)*8 (+ks*32)
  const uint16_t* pa = As + ((wave >> 1) * 64 + (lane & 15)) * 64 + (lane >> 4) * 8;
  const uint16_t* pb = Bs + ((wave &  1) * 64 + (lane & 15)) * 64 + (lane >> 4) * 8;

  const int KT = K >> 6;
  for (int kt = 0; kt < KT; ++kt){
    __syncthreads();                      // prev tile fully consumed
#pragma unroll
    for (int q = 0; q < 4; ++q){
      gload16B(gA + (size_t)q * 32 * lda, lA + q * 2048);
      gload16B(gB + (size_t)q * 32 * K,   lB + q * 2048);
    }
    gA += 64; gB += 64;
    __syncthreads();                      // drains vmcnt -> tile resident
#pragma unroll
    for (int ks = 0; ks < 2; ++ks){
      i32x4 af[4], bf[4];
#pragma unroll
      for (int i = 0; i < 4; ++i) af[i] = *(const i32x4*)(pa + i * 1024 + ks * 32);
#pragma unroll
      for (int j = 0; j < 4; ++j) bf[j] = *(const i32x4*)(pb + j * 1024 + ks * 32);
#pragma unroll
      for (int i = 0; i < 4; ++i)
#pragma unroll
        for (int j = 0; j < 4; ++j)
          asm("v_mfma_f32_16x16x32_bf16 %0, %1, %2, %0"
              : "+v"(acc[i][j]) : "v"(af[i]), "v"(bf[j]));
    }
  }

  asm volatile("s_nop 7\n\ts_nop 7" ::);   // MFMA->VALU read hazard guard

  // C/D layout: col = lane&15, row = (lane>>4)*4 + reg   [m89-verified]
  const int orow0 = m0 + (wave >> 1) * 64 + (lane >> 4) * 4;
  const int ocol0 = n0 + (wave &  1) * 64 + (lane & 15);

  if constexpr (MODE == 0){
    uint16_t* O = (uint16_t*)Obase_ + (size_t)z * o_stride;
#pragma unroll
    for (int i = 0; i < 4; ++i)
#pragma unroll
      for (int j = 0; j < 4; ++j){
        const int col = ocol0 + j * 16;
#pragma unroll
        for (int r = 0; r < 4; ++r){
          const int row = orow0 + i * 16 + r;
          const float v = acc[i][j][r];
          O[(size_t)row * ldo + col] = f2b(v > 0.f ? v : 0.f);
        }
      }
  } else {
    float* O = (float*)Obase_ + (size_t)z * o_stride;
    const float scale = wgate[b * 3 + path];
#pragma unroll
    for (int i = 0; i < 4; ++i)
#pragma unroll
      for (int j = 0; j < 4; ++j){
        const int col = ocol0 + j * 16;
#pragma unroll
        for (int r = 0; r < 4; ++r){
          const int row = orow0 + i * 16 + r;
          const size_t idx = (size_t)row * ldo + col;
          float v = scale * acc[i][j][r];
          if constexpr (MODE == 2) v += O[idx];
          O[idx] = v;
        }
      }
  }
}

// ------------------------------- host ----------------------------------------
extern "C" void kernel_launch(void* const* d_in, const int* in_sizes, int n_in,
                              void* d_out, int out_size, void* d_ws, size_t ws_size,
                              hipStream_t stream)
{
  (void)in_sizes; (void)n_in; (void)out_size;
  const float* x    = (const float*)d_in[0];
  const int*   label= (const int*)d_in[1];
  const float* wi   = (const float*)d_in[2];
  const float* wo   = (const float*)d_in[3];
  const float* swi  = (const float*)d_in[4];
  const float* swo  = (const float*)d_in[5];
  const float* g1   = (const float*)d_in[6];
  const float* g2   = (const float*)d_in[7];
  float* out = (float*)d_out;

  char* ws = (char*)d_ws;
  float* wgate = (float*)ws;                                 // 256 B
  float* gin   = (float*)(ws + 256);                         // B*3*D f32
  float* hbuf  = (float*)(ws + 98560);                       // B*3*F f32
  float* ts    = (float*)(ws + 491776);                      // B*D f32
  float* g1T   = (float*)(ws + (1u << 20));                  // D x 3D f32
  uint16_t* xb = (uint16_t*)(ws + (16u << 20));              // B*S*D bf16
  size_t off = (size_t)(16u << 20) + (size_t)B_ * S_ * D_ * 2;
  uint16_t* wiT  = (uint16_t*)(ws + off); off += (size_t)E_ * D_ * F_ * 2;  // (E,F,D)
  uint16_t* swiT = (uint16_t*)(ws + off); off += (size_t)2  * D_ * F_ * 2;  // (2,F,D)
  uint16_t* woT  = (uint16_t*)(ws + off); off += (size_t)E_ * D_ * F_ * 2;  // (E,D,F)
  uint16_t* swoT = (uint16_t*)(ws + off); off += (size_t)2  * D_ * F_ * 2;  // (2,D,F)
  uint16_t* H    = (uint16_t*)(ws + off);
  const size_t hbytes = (size_t)S_ * F_ * 2;
  const size_t hcap = (ws_size > off) ? (ws_size - off) / hbytes : 0;
  const int nb = hcap >= 8 ? 8 : hcap >= 4 ? 4 : hcap >= 2 ? 2 : 1;

  // prep: x -> bf16; weights -> transposed bf16; g1 -> transposed f32
  cvt_bf16<<<dim3(2048), 256, 0, stream>>>(x, xb, (long)B_ * S_ * D_);
  transpose64<<<dim3(D_/64, F_/64, E_), 256, 0, stream>>>(wi,  wiT,  D_, F_);
  transpose64<<<dim3(D_/64, F_/64, 2 ), 256, 0, stream>>>(swi, swiT, D_, F_);
  transpose64<<<dim3(F_/64, D_/64, E_), 256, 0, stream>>>(wo,  woT,  F_, D_);
  transpose64<<<dim3(F_/64, D_/64, 2 ), 256, 0, stream>>>(swo, swoT, F_, D_);
  transpose_f32<<<dim3(3*D_/64, D_/64), 256, 0, stream>>>(g1, g1T, 3*D_, D_);

  // gate: row-0 outputs -> gin -> ts -> softmax weights (wave-per-row GEMVs)
  gate_h  <<<dim3(F_/4, 3, B_), 256, 0, stream>>>(xb, wiT, swiT, label, hbuf);
  gate_row<<<dim3(D_/4, 3, B_), 256, 0, stream>>>(woT, swoT, label, hbuf, gin);
  gate_w1 <<<dim3(D_/4, B_),    256, 0, stream>>>(gin, g1T, ts);
  gate_w2 <<<dim3(B_),          256, 0, stream>>>(ts, g2, wgate);

  const size_t SD = (size_t)S_ * D_;
  const size_t SF = (size_t)S_ * F_;
  for (int path = 0; path < 3; ++path){
    for (int b0 = 0; b0 < B_; b0 += nb){
      const int nbc = (b0 + nb <= B_) ? nb : (B_ - b0);
      gemm_bt<0><<<dim3(S_/128, F_/128, nbc), 256, 0, stream>>>(
          xb + (size_t)b0 * SD, SD, D_, D_, wiT, swiT, path, b0, label,
          (const float*)nullptr, H, SF, F_);
      if (path == 0)
        gemm_bt<1><<<dim3(S_/128, D_/128, nbc), 256, 0, stream>>>(
            H, SF, F_, F_, woT, swoT, path, b0, label, wgate,
            out + (size_t)b0 * SD, SD, D_);
      else
        gemm_bt<2><<<dim3(S_/128, D_/128, nbc), 256, 0, stream>>>(
            H, SF, F_, F_, woT, swoT, path, b0, label, wgate,
            out + (size_t)b0 * SD, SD, D_);
    }
  }
}

// Round 11
// 1122.285 us; speedup vs baseline: 1.1940x; 1.0332x over previous
//
#include <hip/hip_runtime.h>
#include <hip/hip_bf16.h>
#include <cstdint>

#define B_ 8
#define S_ 2048
#define D_ 1024
#define F_ 4096
#define E_ 5

typedef __attribute__((ext_vector_type(4))) int      i32x4;
typedef __attribute__((ext_vector_type(4))) float    f32x4;
typedef __attribute__((ext_vector_type(4))) uint16_t u16x4;
typedef __attribute__((ext_vector_type(8))) uint16_t u16x8;

__device__ __forceinline__ float b2f(uint16_t u){
  union { uint32_t i; float f; } v; v.i = ((uint32_t)u) << 16; return v.f;
}
__device__ __forceinline__ uint16_t f2b(float f){
  union { float f; uint32_t i; } v; v.f = f;
  uint32_t x = v.i;
  uint32_t r = (x + 0x7FFFu + ((x >> 16) & 1u)) >> 16;
  return (uint16_t)r;
}
// direct global->LDS DMA, 16B per lane; lds ptr must be wave-uniform base
__device__ __forceinline__ void gload16B(const uint16_t* g, uint16_t* l){
  __builtin_amdgcn_global_load_lds(
      (const __attribute__((address_space(1))) void*)g,
      (__attribute__((address_space(3))) void*)l, 16, 0, 0);
}

// -------- x f32 -> bf16 ------------------------------------------------------
__global__ __launch_bounds__(256) void cvt_bf16(
    const float* __restrict__ src, uint16_t* __restrict__ dst, long n)
{
  long i = ((long)blockIdx.x * 256 + threadIdx.x) * 8;
  const long stride = (long)gridDim.x * 256 * 8;
  for (; i + 8 <= n; i += stride){
    f32x4 a = *(const f32x4*)(src + i);
    f32x4 b = *(const f32x4*)(src + i + 4);
    u16x8 r;
#pragma unroll
    for (int k = 0; k < 4; ++k){ r[k] = f2b(a[k]); r[4 + k] = f2b(b[k]); }
    *(u16x8*)(dst + i) = r;
  }
}

// -------- transpose+cvt: src f32 (R,C) -> dst bf16 (C,R), per blockIdx.z -----
__global__ __launch_bounds__(256) void transpose64(
    const float* __restrict__ src, uint16_t* __restrict__ dst, int R, int C)
{
  __shared__ uint16_t t[64][68];
  const size_t base = (size_t)blockIdx.z * R * C;
  const int r0 = blockIdx.x * 64, c0 = blockIdx.y * 64;
  const int tr = threadIdx.x >> 4;
  const int tc = (threadIdx.x & 15) * 4;
#pragma unroll
  for (int i = 0; i < 4; ++i){
    const int row = tr + i * 16;
    f32x4 v = *(const f32x4*)(src + base + (size_t)(r0 + row) * C + (c0 + tc));
    t[row][tc + 0] = f2b(v[0]); t[row][tc + 1] = f2b(v[1]);
    t[row][tc + 2] = f2b(v[2]); t[row][tc + 3] = f2b(v[3]);
  }
  __syncthreads();
#pragma unroll
  for (int i = 0; i < 4; ++i){
    const int orow = tr + i * 16;
    u16x4 v;
    v[0] = t[tc + 0][orow]; v[1] = t[tc + 1][orow];
    v[2] = t[tc + 2][orow]; v[3] = t[tc + 3][orow];
    *(u16x4*)(dst + base + (size_t)(c0 + orow) * R + (r0 + tc)) = v;
  }
}

// -------- transpose f32 (R,C) -> f32 (C,R) (for g1) --------------------------
__global__ __launch_bounds__(256) void transpose_f32(
    const float* __restrict__ src, float* __restrict__ dst, int R, int C)
{
  __shared__ float t[64][65];
  const int r0 = blockIdx.x * 64, c0 = blockIdx.y * 64;
  const int tr = threadIdx.x >> 4;
  const int tc = (threadIdx.x & 15) * 4;
#pragma unroll
  for (int i = 0; i < 4; ++i){
    const int row = tr + i * 16;
    f32x4 v = *(const f32x4*)(src + (size_t)(r0 + row) * C + (c0 + tc));
    t[row][tc + 0] = v[0]; t[row][tc + 1] = v[1];
    t[row][tc + 2] = v[2]; t[row][tc + 3] = v[3];
  }
  __syncthreads();
#pragma unroll
  for (int i = 0; i < 4; ++i){
    const int orow = tr + i * 16;
    f32x4 v;
    v[0] = t[tc + 0][orow]; v[1] = t[tc + 1][orow];
    v[2] = t[tc + 2][orow]; v[3] = t[tc + 3][orow];
    *(f32x4*)(dst + (size_t)(c0 + orow) * R + (r0 + tc)) = v;
  }
}

// ---- gate 1 (wave-per-f): h[b,path,f] = relu(dot(x[b,0,:], W1row_f)) --------
__global__ __launch_bounds__(256) void gate_h(
    const uint16_t* __restrict__ xb, const uint16_t* __restrict__ wiT,
    const uint16_t* __restrict__ swiT, const int* __restrict__ label,
    float* __restrict__ hbuf)
{
  const int wv = threadIdx.x >> 6, lane = threadIdx.x & 63;
  const int f = blockIdx.x * 4 + wv;          // grid.x = F/4
  const int path = blockIdx.y, b = blockIdx.z;
  const uint16_t* wrow = (path == 0)
      ? wiT  + ((size_t)label[b] * F_ + f) * D_
      : swiT + ((size_t)(path - 1) * F_ + f) * D_;
  const uint16_t* xr = xb + (size_t)b * S_ * D_;   // row 0 of batch b
  float acc = 0.f;
#pragma unroll
  for (int c = 0; c < 2; ++c){                 // D=1024 = 2 x (64 lanes x 8)
    const int off = c * 512 + lane * 8;
    u16x8 w  = *(const u16x8*)(wrow + off);
    u16x8 xv = *(const u16x8*)(xr + off);
#pragma unroll
    for (int k = 0; k < 8; ++k) acc += b2f(xv[k]) * b2f(w[k]);
  }
#pragma unroll
  for (int o = 32; o > 0; o >>= 1) acc += __shfl_down(acc, o);
  if (lane == 0)
    hbuf[(size_t)(b * 3 + path) * F_ + f] = fmaxf(acc, 0.f);
}

// ---- gate 2 (wave-per-d): gin[b,path,d] = dot(h[b,path,:], W2row_d) ---------
__global__ __launch_bounds__(256) void gate_row(
    const uint16_t* __restrict__ woT, const uint16_t* __restrict__ swoT,
    const int* __restrict__ label, const float* __restrict__ hbuf,
    float* __restrict__ gin)
{
  const int wv = threadIdx.x >> 6, lane = threadIdx.x & 63;
  const int d = blockIdx.x * 4 + wv;          // grid.x = D/4
  const int path = blockIdx.y, b = blockIdx.z;
  const uint16_t* wrow = (path == 0)
      ? woT  + ((size_t)label[b] * D_ + d) * F_
      : swoT + ((size_t)(path - 1) * D_ + d) * F_;
  const float* hb = hbuf + (size_t)(b * 3 + path) * F_;
  float acc = 0.f;
#pragma unroll
  for (int c = 0; c < 8; ++c){                 // F=4096 = 8 x (64 lanes x 8)
    const int off = c * 512 + lane * 8;
    u16x8 w  = *(const u16x8*)(wrow + off);
    f32x4 h0 = *(const f32x4*)(hb + off);
    f32x4 h1 = *(const f32x4*)(hb + off + 4);
    acc += h0[0]*b2f(w[0]) + h0[1]*b2f(w[1]) + h0[2]*b2f(w[2]) + h0[3]*b2f(w[3])
         + h1[0]*b2f(w[4]) + h1[1]*b2f(w[5]) + h1[2]*b2f(w[6]) + h1[3]*b2f(w[7]);
  }
#pragma unroll
  for (int o = 32; o > 0; o >>= 1) acc += __shfl_down(acc, o);
  if (lane == 0)
    gin[(size_t)(b * 3 + path) * D_ + d] = acc;
}

// ---- gate 3a (wave-per-j): ts[b,j] = relu(dot(gin[b,:], g1Trow_j)) ----------
__global__ __launch_bounds__(256) void gate_w1(
    const float* __restrict__ gin, const float* __restrict__ g1T,
    float* __restrict__ ts)
{
  const int wv = threadIdx.x >> 6, lane = threadIdx.x & 63;
  const int j = blockIdx.x * 4 + wv;          // grid.x = D/4
  const int b = blockIdx.y;
  const float* grow = g1T + (size_t)j * (3 * D_);
  const float* g = gin + (size_t)b * 3 * D_;
  float acc = 0.f;
#pragma unroll
  for (int c = 0; c < 12; ++c){                // 3D=3072 = 12 x (64 lanes x 4)
    const int off = c * 256 + lane * 4;
    f32x4 w  = *(const f32x4*)(grow + off);
    f32x4 gv = *(const f32x4*)(g + off);
    acc += gv[0]*w[0] + gv[1]*w[1] + gv[2]*w[2] + gv[3]*w[3];
  }
#pragma unroll
  for (int o = 32; o > 0; o >>= 1) acc += __shfl_down(acc, o);
  if (lane == 0)
    ts[(size_t)b * D_ + j] = fmaxf(acc, 0.f);
}

// -------- gate 3b: wgate[b,:] = softmax(ts[b,:] @ g2) ------------------------
__global__ __launch_bounds__(256) void gate_w2(
    const float* __restrict__ ts, const float* __restrict__ g2,
    float* __restrict__ wgate)
{
  const int b = blockIdx.x;
  __shared__ float p0[256], p1[256], p2[256];
  const float* t = ts + (size_t)b * D_;
  float s0 = 0.f, s1 = 0.f, s2 = 0.f;
  const int j0 = threadIdx.x * 4;
#pragma unroll
  for (int jj = 0; jj < 4; ++jj){
    const float tv = t[j0 + jj];
    s0 += tv * g2[(j0 + jj) * 3 + 0];
    s1 += tv * g2[(j0 + jj) * 3 + 1];
    s2 += tv * g2[(j0 + jj) * 3 + 2];
  }
  p0[threadIdx.x] = s0; p1[threadIdx.x] = s1; p2[threadIdx.x] = s2;
  __syncthreads();
  for (int st = 128; st > 0; st >>= 1){
    if (threadIdx.x < st){
      p0[threadIdx.x] += p0[threadIdx.x + st];
      p1[threadIdx.x] += p1[threadIdx.x + st];
      p2[threadIdx.x] += p2[threadIdx.x + st];
    }
    __syncthreads();
  }
  if (threadIdx.x == 0){
    const float a = p0[0], c = p1[0], d = p2[0];
    const float m = fmaxf(a, fmaxf(c, d));
    const float e0 = expf(a - m), e1 = expf(c - m), e2 = expf(d - m);
    const float inv = 1.f / (e0 + e1 + e2);
    wgate[b * 3 + 0] = e0 * inv;
    wgate[b * 3 + 1] = e1 * inv;
    wgate[b * 3 + 2] = e2 * inv;
  }
}

// ---------------- main GEMM: C(128x128) per block, A(M,K) x BT(N,K)^T --------
// Round-3/8/10 verified structure EXACT, but __launch_bounds__(256, 4):
// unified VGPR+AGPR file (~150-170/thread unconstrained) was capping
// residency at 3 blocks/CU (the measured 37% occupancy); forcing a
// 128-unified-reg budget (acc 64 + frags 16 + addr ~30 fits) allows 4
// blocks/CU -> +33% cross-block latency hiding for the vmcnt(0) drain.
// MODE 0: H = relu(A@B) bf16 | MODE 1: O = s*(A@B) f32 | MODE 2: O += s*(A@B)
template<int MODE>
__global__ __launch_bounds__(256, 4) void gemm_bt(
    const uint16_t* __restrict__ Abase, size_t a_stride, int lda, int K,
    const uint16_t* __restrict__ Wexp, const uint16_t* __restrict__ Wsh,
    int path, int b0, const int* __restrict__ label,
    const float* __restrict__ wgate,
    void* __restrict__ Obase_, size_t o_stride, int ldo)
{
  __shared__ uint16_t As[128 * 64];   // [m 128][k 64] linear
  __shared__ uint16_t Bs[128 * 64];   // [n 128][k 64] linear

  const int z  = blockIdx.z;
  const int b  = b0 + z;
  const int m0 = blockIdx.x * 128;
  const int n0 = blockIdx.y * 128;

  const uint16_t* A = Abase + (size_t)z * a_stride;
  const size_t wstride = (size_t)D_ * F_;
  const uint16_t* BT = (path == 0) ? Wexp + (size_t)label[b] * wstride
                                   : Wsh  + (size_t)(path - 1) * wstride;

  const int tid  = threadIdx.x;
  const int wave = tid >> 6;
  const int lane = tid & 63;

  // global addresses: per-lane; LDS dest: wave-uniform base (+lane*16B by HW)
  const uint16_t* gA = A  + (size_t)(m0 + wave * 8 + (lane >> 3)) * lda + (lane & 7) * 8;
  const uint16_t* gB = BT + (size_t)(n0 + wave * 8 + (lane >> 3)) * K   + (lane & 7) * 8;
  uint16_t* lA = As + wave * 512;
  uint16_t* lB = Bs + wave * 512;

  f32x4 acc[4][4];
#pragma unroll
  for (int i = 0; i < 4; ++i)
#pragma unroll
    for (int j = 0; j < 4; ++j) acc[i][j] = (f32x4)0.0f;

  // fragment read bases: row = lane&15, k = (lane>>4)*8 (+ks*32)
  const uint16_t* pa = As + ((wave >> 1) * 64 + (lane & 15)) * 64 + (lane >> 4) * 8;
  const uint16_t* pb = Bs + ((wave &  1) * 64 + (lane & 15)) * 64 + (lane >> 4) * 8;

  const int KT = K >> 6;
  for (int kt = 0; kt < KT; ++kt){
    __syncthreads();                      // prev tile fully consumed
#pragma unroll
    for (int q = 0; q < 4; ++q){
      gload16B(gA + (size_t)q * 32 * lda, lA + q * 2048);
      gload16B(gB + (size_t)q * 32 * K,   lB + q * 2048);
    }
    gA += 64; gB += 64;
    __syncthreads();                      // drains vmcnt -> tile resident
#pragma unroll
    for (int ks = 0; ks < 2; ++ks){
      i32x4 af[4], bf[4];
#pragma unroll
      for (int i = 0; i < 4; ++i) af[i] = *(const i32x4*)(pa + i * 1024 + ks * 32);
#pragma unroll
      for (int j = 0; j < 4; ++j) bf[j] = *(const i32x4*)(pb + j * 1024 + ks * 32);
#pragma unroll
      for (int i = 0; i < 4; ++i)
#pragma unroll
        for (int j = 0; j < 4; ++j)
          asm("v_mfma_f32_16x16x32_bf16 %0, %1, %2, %0"
              : "+v"(acc[i][j]) : "v"(af[i]), "v"(bf[j]));
    }
  }

  asm volatile("s_nop 7\n\ts_nop 7" ::);   // MFMA->VALU read hazard guard

  // C/D layout: col = lane&15, row = (lane>>4)*4 + reg   [m89-verified]
  const int orow0 = m0 + (wave >> 1) * 64 + (lane >> 4) * 4;
  const int ocol0 = n0 + (wave &  1) * 64 + (lane & 15);

  if constexpr (MODE == 0){
    uint16_t* O = (uint16_t*)Obase_ + (size_t)z * o_stride;
#pragma unroll
    for (int i = 0; i < 4; ++i)
#pragma unroll
      for (int j = 0; j < 4; ++j){
        const int col = ocol0 + j * 16;
#pragma unroll
        for (int r = 0; r < 4; ++r){
          const int row = orow0 + i * 16 + r;
          const float v = acc[i][j][r];
          O[(size_t)row * ldo + col] = f2b(v > 0.f ? v : 0.f);
        }
      }
  } else {
    float* O = (float*)Obase_ + (size_t)z * o_stride;
    const float scale = wgate[b * 3 + path];
#pragma unroll
    for (int i = 0; i < 4; ++i)
#pragma unroll
      for (int j = 0; j < 4; ++j){
        const int col = ocol0 + j * 16;
#pragma unroll
        for (int r = 0; r < 4; ++r){
          const int row = orow0 + i * 16 + r;
          const size_t idx = (size_t)row * ldo + col;
          float v = scale * acc[i][j][r];
          if constexpr (MODE == 2) v += O[idx];
          O[idx] = v;
        }
      }
  }
}

// ------------------------------- host ----------------------------------------
extern "C" void kernel_launch(void* const* d_in, const int* in_sizes, int n_in,
                              void* d_out, int out_size, void* d_ws, size_t ws_size,
                              hipStream_t stream)
{
  (void)in_sizes; (void)n_in; (void)out_size;
  const float* x    = (const float*)d_in[0];
  const int*   label= (const int*)d_in[1];
  const float* wi   = (const float*)d_in[2];
  const float* wo   = (const float*)d_in[3];
  const float* swi  = (const float*)d_in[4];
  const float* swo  = (const float*)d_in[5];
  const float* g1   = (const float*)d_in[6];
  const float* g2   = (const float*)d_in[7];
  float* out = (float*)d_out;

  char* ws = (char*)d_ws;
  float* wgate = (float*)ws;                                 // 256 B
  float* gin   = (float*)(ws + 256);                         // B*3*D f32
  float* hbuf  = (float*)(ws + 98560);                       // B*3*F f32
  float* ts    = (float*)(ws + 491776);                      // B*D f32
  float* g1T   = (float*)(ws + (1u << 20));                  // D x 3D f32
  uint16_t* xb = (uint16_t*)(ws + (16u << 20));              // B*S*D bf16
  size_t off = (size_t)(16u << 20) + (size_t)B_ * S_ * D_ * 2;
  uint16_t* wiT  = (uint16_t*)(ws + off); off += (size_t)E_ * D_ * F_ * 2;  // (E,F,D)
  uint16_t* swiT = (uint16_t*)(ws + off); off += (size_t)2  * D_ * F_ * 2;  // (2,F,D)
  uint16_t* woT  = (uint16_t*)(ws + off); off += (size_t)E_ * D_ * F_ * 2;  // (E,D,F)
  uint16_t* swoT = (uint16_t*)(ws + off); off += (size_t)2  * D_ * F_ * 2;  // (2,D,F)
  uint16_t* H    = (uint16_t*)(ws + off);
  const size_t hbytes = (size_t)S_ * F_ * 2;
  const size_t hcap = (ws_size > off) ? (ws_size - off) / hbytes : 0;
  const int nb = hcap >= 8 ? 8 : hcap >= 4 ? 4 : hcap >= 2 ? 2 : 1;

  // prep: x -> bf16; weights -> transposed bf16; g1 -> transposed f32
  cvt_bf16<<<dim3(2048), 256, 0, stream>>>(x, xb, (long)B_ * S_ * D_);
  transpose64<<<dim3(D_/64, F_/64, E_), 256, 0, stream>>>(wi,  wiT,  D_, F_);
  transpose64<<<dim3(D_/64, F_/64, 2 ), 256, 0, stream>>>(swi, swiT, D_, F_);
  transpose64<<<dim3(F_/64, D_/64, E_), 256, 0, stream>>>(wo,  woT,  F_, D_);
  transpose64<<<dim3(F_/64, D_/64, 2 ), 256, 0, stream>>>(swo, swoT, F_, D_);
  transpose_f32<<<dim3(3*D_/64, D_/64), 256, 0, stream>>>(g1, g1T, 3*D_, D_);

  // gate: row-0 outputs -> gin -> ts -> softmax weights (wave-per-row GEMVs)
  gate_h  <<<dim3(F_/4, 3, B_), 256, 0, stream>>>(xb, wiT, swiT, label, hbuf);
  gate_row<<<dim3(D_/4, 3, B_), 256, 0, stream>>>(woT, swoT, label, hbuf, gin);
  gate_w1 <<<dim3(D_/4, B_),    256, 0, stream>>>(gin, g1T, ts);
  gate_w2 <<<dim3(B_),          256, 0, stream>>>(ts, g2, wgate);

  const size_t SD = (size_t)S_ * D_;
  const size_t SF = (size_t)S_ * F_;
  for (int path = 0; path < 3; ++path){
    for (int b0 = 0; b0 < B_; b0 += nb){
      const int nbc = (b0 + nb <= B_) ? nb : (B_ - b0);
      gemm_bt<0><<<dim3(S_/128, F_/128, nbc), 256, 0, stream>>>(
          xb + (size_t)b0 * SD, SD, D_, D_, wiT, swiT, path, b0, label,
          (const float*)nullptr, H, SF, F_);
      if (path == 0)
        gemm_bt<1><<<dim3(S_/128, D_/128, nbc), 256, 0, stream>>>(
            H, SF, F_, F_, woT, swoT, path, b0, label, wgate,
            out + (size_t)b0 * SD, SD, D_);
      else
        gemm_bt<2><<<dim3(S_/128, D_/128, nbc), 256, 0, stream>>>(
            H, SF, F_, F_, woT, swoT, path, b0, label, wgate,
            out + (size_t)b0 * SD, SD, D_);
    }
  }
}